// Round 3
// baseline (258.834 us; speedup 1.0000x reference)
//
#include <hip/hip_runtime.h>
#include <hip/hip_fp16.h>

// Problem constants: B=2, CIN=32, COUT=64, K=9, H=256, W=512, OH=256, OW=512
#define HW_IN   131072
#define W_IN    512
#define H_IN    256
#define HW_OUT  131072
#define CIN     32
#define COUT    64
#define KK      9
#define BB      2

typedef _Float16 hf2 __attribute__((ext_vector_type(2)));
typedef _Float16 hf8 __attribute__((ext_vector_type(8)));
typedef float f32x4 __attribute__((ext_vector_type(4)));

static __device__ __forceinline__ hf8 u4h(uint4 u) {
  return __builtin_bit_cast(hf8, u);
}

// ---------------------------------------------------------------------------
// Kernel 1: LDS-tiled transpose x (B,CIN,H*W) fp32 -> xt (H*W, B, CIN) f16.
// Tile = 128 hw x 64 bc (bc = b*32+c = both x's leading dims and the output
// half-position within a pixel). Phase 1: coalesced float2 reads along hw,
// f16 scatter into LDS rows [pixel][bc] (row stride 72 halves = 36 dwords,
// 16B-aligned; dword-level XOR swizzle by (p>>1)&28 keeps write conflicts
// ~8-way on 2B writes, ~90 cyc/wave total). Phase 2: ds_read_b128 + fully
// contiguous uint4 global stores (each wave stores a contiguous 4KB run).
// ---------------------------------------------------------------------------
__global__ __launch_bounds__(256) void transpose_f16_lds(
    const float* __restrict__ x, _Float16* __restrict__ xt) {
  __shared__ __align__(16) _Float16 tile[128 * 72];  // 18 KB

  int t   = threadIdx.x;
  int hw0 = blockIdx.x * 128;
  int hp  = t & 63;    // hw-pair within tile (pixels 2hp, 2hp+1)
  int bch = t >> 6;    // 0..3: bc group

  unsigned sw = (unsigned)(hp & 28);  // xor key, = (p>>1)&28 for both pixels

#pragma unroll
  for (int i = 0; i < 16; ++i) {
    int bc = bch * 16 + i;
    float2 v = *(const float2*)(x + (size_t)bc * HW_IN + hw0 + 2 * hp);
    unsigned dw = ((unsigned)bc >> 1) ^ sw;   // swizzled dword-in-row
    unsigned lo = (unsigned)bc & 1u;
    tile[(2 * hp + 0) * 72 + 2 * dw + lo] = (_Float16)v.x;
    tile[(2 * hp + 1) * 72 + 2 * dw + lo] = (_Float16)v.y;
  }
  __syncthreads();

  const unsigned* tl = (const unsigned*)tile;
  uint4* xt4 = (uint4*)xt;
#pragma unroll
  for (int pass = 0; pass < 4; ++pass) {
    int p  = pass * 32 + (t >> 3);
    int c8 = t & 7;
    unsigned key = (unsigned)((p >> 1) & 28);
    unsigned dwi = (unsigned)p * 36u + (((unsigned)c8 * 4u) ^ key);
    uint4 v = *(const uint4*)(tl + dwi);
    xt4[(size_t)(hw0 + p) * 8 + c8] = v;
  }
}

// ---------------------------------------------------------------------------
// Kernel 2: fused gather + MFMA contraction (512-thread blocks -> 32 waves/CU).
// GEMM view: out[pix, o] = sum_{ck=k*32+c} samp[pix, ck] * W[o, ck].
// One wave = 16 pixels x 64 couts (4 N-tiles), K=288 = 9 taps x 32 channels.
// A-frag 16x16x32 f16: lane m=lane&15 -> pixel, quad=lane>>4 -> channel
// quarter; corner gather = one 64B line per 4-lane set. B-frags from LDS
// [k][o][c] f16 (36KB): per (k,N-tile) a contiguous 1KB region read
// disjointly. LDS 36KB -> 4 blocks/CU x 8 waves = 32 waves/CU (100% occ);
// VGPR must stay <=64 -> __launch_bounds__(512, 8).
// ---------------------------------------------------------------------------
__global__ __launch_bounds__(512, 8) void mapped_conv_mfma(
    const _Float16* __restrict__ xt,
    const float* __restrict__ weight,   // [COUT][CIN][KK] fp32
    const float* __restrict__ bias,     // [COUT]
    const float* __restrict__ sm,       // [HW_OUT][KK][2] fp32
    float* __restrict__ out) {          // [BB][COUT][HW_OUT] fp32
  __shared__ __align__(16) _Float16 w_lds[KK * COUT * CIN];  // 36 KB

  int t = threadIdx.x;
  // Stage weights: w_lds[(k*64 + o)*32 + c] = W[o][c][k] as f16.
  for (int j = t; j < COUT * CIN * KK; j += 512) {
    unsigned ju = (unsigned)j;
    unsigned o  = ju / 288u;
    unsigned rr = ju % 288u;
    unsigned c  = rr / 9u;
    unsigned k  = rr % 9u;
    w_lds[(k * 64u + o) * 32u + c] = (_Float16)weight[ju];
  }
  __syncthreads();

  int wave = t >> 6;      // 0..7
  int lane = t & 63;
  int m    = lane & 15;   // A-row: pixel; B-col: cout within N-tile
  int quad = lane >> 4;   // channel quarter (A) / k-chunk (B) / row group (C)

  int pix_base = blockIdx.x * 128 + wave * 16;    // 2048 blocks x 8 waves
  int pix  = pix_base + m;
  int b    = pix_base >> 17;                      // wave-uniform
  int hw   = pix & (HW_OUT - 1);
  int hw_base = pix_base & (HW_OUT - 1);

  const uint4* xt4 = (const uint4*)xt;
  int bq = b * 4 + quad;   // uint4-granule within a pixel's 64 halves

  f32x4 acc[4] = {{0.f,0.f,0.f,0.f},{0.f,0.f,0.f,0.f},
                  {0.f,0.f,0.f,0.f},{0.f,0.f,0.f,0.f}};

  const float* smp = sm + (size_t)hw * (KK * 2);
  const uint4* wbl = (const uint4*)w_lds + (size_t)(m * 4 + quad);

#pragma unroll 3
  for (int k = 0; k < KK; ++k) {
    float sx = smp[k * 2 + 0];
    float sy = smp[k * 2 + 1];
    float bxf = floorf(sx), byf = floorf(sy);
    float fx = sx - bxf, fy = sy - byf;
    int ix0 = (int)bxf, iy0 = (int)byf;
    int ix1 = min(ix0 + 1, W_IN - 1);
    int iy1 = min(iy0 + 1, H_IN - 1);
    ix0 = max(min(ix0, W_IN - 1), 0); ix1 = max(ix1, 0);
    iy0 = max(min(iy0, H_IN - 1), 0); iy1 = max(iy1, 0);

    uint4 v00 = xt4[(iy0 * W_IN + ix0) * 8 + bq];
    uint4 v01 = xt4[(iy0 * W_IN + ix1) * 8 + bq];
    uint4 v10 = xt4[(iy1 * W_IN + ix0) * 8 + bq];
    uint4 v11 = xt4[(iy1 * W_IN + ix1) * 8 + bq];

    _Float16 w00 = (_Float16)((1.f - fx) * (1.f - fy));
    _Float16 w01 = (_Float16)(fx * (1.f - fy));
    _Float16 w10 = (_Float16)((1.f - fx) * fy);
    _Float16 w11 = (_Float16)(fx * fy);
    hf8 h00 = {w00, w00, w00, w00, w00, w00, w00, w00};
    hf8 h01 = {w01, w01, w01, w01, w01, w01, w01, w01};
    hf8 h10 = {w10, w10, w10, w10, w10, w10, w10, w10};
    hf8 h11 = {w11, w11, w11, w11, w11, w11, w11, w11};

    hf8 a = h00 * u4h(v00) + h01 * u4h(v01) + h10 * u4h(v10) + h11 * u4h(v11);

    const uint4* wk = wbl + (size_t)k * 256;   // per-k block = 64 o * 4 granules
    hf8 b0 = u4h(wk[0]);
    hf8 b1 = u4h(wk[64]);
    hf8 b2 = u4h(wk[128]);
    hf8 b3 = u4h(wk[192]);

    acc[0] = __builtin_amdgcn_mfma_f32_16x16x32_f16(a, b0, acc[0], 0, 0, 0);
    acc[1] = __builtin_amdgcn_mfma_f32_16x16x32_f16(a, b1, acc[1], 0, 0, 0);
    acc[2] = __builtin_amdgcn_mfma_f32_16x16x32_f16(a, b2, acc[2], 0, 0, 0);
    acc[3] = __builtin_amdgcn_mfma_f32_16x16x32_f16(a, b3, acc[3], 0, 0, 0);
  }

  // Epilogue: lane writes 4 consecutive pixels (rows quad*4..+3) for cout n.
  int hw0 = hw_base + quad * 4;
#pragma unroll
  for (int nt = 0; nt < 4; ++nt) {
    int n = nt * 16 + m;
    float bn = bias[n];
    float4 v = make_float4(acc[nt][0] + bn, acc[nt][1] + bn,
                           acc[nt][2] + bn, acc[nt][3] + bn);
    float* op = out + (size_t)(b * COUT + n) * HW_OUT + hw0;
    *(float4*)op = v;
  }
}

extern "C" void kernel_launch(void* const* d_in, const int* in_sizes, int n_in,
                              void* d_out, int out_size, void* d_ws, size_t ws_size,
                              hipStream_t stream) {
  const float* x  = (const float*)d_in[0];   // [B][CIN][H*W]
  const float* w  = (const float*)d_in[1];   // [COUT][CIN][KK]
  const float* bs = (const float*)d_in[2];   // [COUT]
  const float* sm = (const float*)d_in[3];   // [OH*OW][KK][2]
  float* out = (float*)d_out;                // [B][COUT][OH*OW]
  _Float16* xt = (_Float16*)d_ws;            // 16 MB scratch: (H*W, B, CIN) f16

  transpose_f16_lds<<<dim3(1024), dim3(256), 0, stream>>>(x, xt);
  mapped_conv_mfma<<<dim3(2048), dim3(512), 0, stream>>>(xt, w, bs, sm, out);
}

// Round 4
// 258.436 us; speedup vs baseline: 1.0015x; 1.0015x over previous
//
#include <hip/hip_runtime.h>
#include <hip/hip_fp16.h>

// Problem constants: B=2, CIN=32, COUT=64, K=9, H=256, W=512, OH=256, OW=512
#define HW_IN   131072
#define W_IN    512
#define H_IN    256
#define HW_OUT  131072
#define CIN     32
#define COUT    64
#define KK      9
#define BB      2

typedef _Float16 hf2 __attribute__((ext_vector_type(2)));
typedef _Float16 hf8 __attribute__((ext_vector_type(8)));
typedef float f32x4 __attribute__((ext_vector_type(4)));

static __device__ __forceinline__ hf8 u4h(uint4 u) {
  return __builtin_bit_cast(hf8, u);
}

// ---------------------------------------------------------------------------
// Kernel 1: LDS-tiled transpose x (B,CIN,H*W) fp32 -> xt (H*W, B, CIN) f16.
// Phase 1: coalesced float2 reads along hw, f16 scatter into LDS (XOR
// swizzle keeps write conflicts bounded). Phase 2: ds_read_b128 + fully
// contiguous uint4 global stores (each wave stores a contiguous 1KB run).
// ---------------------------------------------------------------------------
__global__ __launch_bounds__(256) void transpose_f16_lds(
    const float* __restrict__ x, _Float16* __restrict__ xt) {
  __shared__ __align__(16) _Float16 tile[128 * 72];  // 18 KB

  int t   = threadIdx.x;
  int hw0 = blockIdx.x * 128;
  int hp  = t & 63;    // hw-pair within tile (pixels 2hp, 2hp+1)
  int bch = t >> 6;    // 0..3: bc group

  unsigned sw = (unsigned)(hp & 28);  // xor key, = (p>>1)&28 for both pixels

#pragma unroll
  for (int i = 0; i < 16; ++i) {
    int bc = bch * 16 + i;
    float2 v = *(const float2*)(x + (size_t)bc * HW_IN + hw0 + 2 * hp);
    unsigned dw = ((unsigned)bc >> 1) ^ sw;   // swizzled dword-in-row
    unsigned lo = (unsigned)bc & 1u;
    tile[(2 * hp + 0) * 72 + 2 * dw + lo] = (_Float16)v.x;
    tile[(2 * hp + 1) * 72 + 2 * dw + lo] = (_Float16)v.y;
  }
  __syncthreads();

  const unsigned* tl = (const unsigned*)tile;
  uint4* xt4 = (uint4*)xt;
#pragma unroll
  for (int pass = 0; pass < 4; ++pass) {
    int p  = pass * 32 + (t >> 3);
    int c8 = t & 7;
    unsigned key = (unsigned)((p >> 1) & 28);
    unsigned dwi = (unsigned)p * 36u + (((unsigned)c8 * 4u) ^ key);
    uint4 v = *(const uint4*)(tl + dwi);
    xt4[(size_t)(hw0 + p) * 8 + c8] = v;
  }
}

// ---------------------------------------------------------------------------
// Kernel 2: fused gather + MFMA contraction.
// GEMM view: out[pix, o] = sum_{ck=k*32+c} samp[pix, ck] * W[o, ck].
// One wave = 16 pixels x 64 couts (4 N-tiles), K=288 = 9 taps x 32 channels.
// A-frag 16x16x32 f16: lane m=lane&15 -> pixel, quad=lane>>4 -> channel
// quarter; corner gather = one 64B line per 4-lane set. B-frags from LDS
// [k][o][c] f16 (36KB, conflict-free disjoint reads).
//
// Latency plan (this round's change): kernel is gather-latency-bound.
//  - __launch_bounds__(512, 6): 3 blocks/CU x 8 waves = 24 waves/CU AND
//    VGPR budget ~85 (R3's (512,8) squeezed VGPR to 32 and halved MLP).
//  - All 9 taps' sample coords preloaded up-front (removes sm-load from
//    every tap's critical path).
//  - Depth-1 corner prefetch: tap k+1's 4 corner loads issue before tap k's
//    A-assembly/MFMAs -> 4-8 loads always in flight per wave.
// ---------------------------------------------------------------------------
__global__ __launch_bounds__(512, 6) void mapped_conv_mfma(
    const _Float16* __restrict__ xt,
    const float* __restrict__ weight,   // [COUT][CIN][KK] fp32
    const float* __restrict__ bias,     // [COUT]
    const float* __restrict__ sm,       // [HW_OUT][KK][2] fp32
    float* __restrict__ out) {          // [BB][COUT][HW_OUT] fp32
  __shared__ __align__(16) _Float16 w_lds[KK * COUT * CIN];  // 36 KB

  int t = threadIdx.x;
  // Stage weights: w_lds[(k*64 + o)*32 + c] = W[o][c][k] as f16.
  for (int j = t; j < COUT * CIN * KK; j += 512) {
    unsigned ju = (unsigned)j;
    unsigned o  = ju / 288u;
    unsigned rr = ju % 288u;
    unsigned c  = rr / 9u;
    unsigned k  = rr % 9u;
    w_lds[(k * 64u + o) * 32u + c] = (_Float16)weight[ju];
  }
  __syncthreads();

  int wave = t >> 6;      // 0..7
  int lane = t & 63;
  int m    = lane & 15;   // A-row: pixel; B-col: cout within N-tile
  int quad = lane >> 4;   // channel quarter (A) / k-chunk (B) / row group (C)

  int pix_base = blockIdx.x * 128 + wave * 16;    // 2048 blocks x 8 waves
  int pix  = pix_base + m;
  int b    = pix_base >> 17;                      // wave-uniform
  int hw   = pix & (HW_OUT - 1);
  int hw_base = pix_base & (HW_OUT - 1);

  const uint4* xt4 = (const uint4*)xt;
  int bq = b * 4 + quad;   // uint4-granule within a pixel's 64 halves

  // Preload ALL taps' sample coords (9 x float2 = 18 VGPRs, issued together).
  const float* smp = sm + (size_t)hw * (KK * 2);
  float2 s[KK];
#pragma unroll
  for (int k = 0; k < KK; ++k) s[k] = *(const float2*)(smp + k * 2);

  f32x4 acc[4] = {{0.f,0.f,0.f,0.f},{0.f,0.f,0.f,0.f},
                  {0.f,0.f,0.f,0.f},{0.f,0.f,0.f,0.f}};

  const uint4* wbl = (const uint4*)w_lds + (size_t)(m * 4 + quad);

  // Corner-address helper (coords are in-range by construction; clamps cheap).
  auto taps = [&](int k, int& g00, int& g01, int& g10, int& g11) {
    float bxf = floorf(s[k].x), byf = floorf(s[k].y);
    int ix0 = (int)bxf, iy0 = (int)byf;
    int ix1 = min(ix0 + 1, W_IN - 1);
    int iy1 = min(iy0 + 1, H_IN - 1);
    ix0 = max(min(ix0, W_IN - 1), 0); ix1 = max(ix1, 0);
    iy0 = max(min(iy0, H_IN - 1), 0); iy1 = max(iy1, 0);
    int r0 = iy0 * W_IN, r1 = iy1 * W_IN;
    g00 = (r0 + ix0) * 8 + bq; g01 = (r0 + ix1) * 8 + bq;
    g10 = (r1 + ix0) * 8 + bq; g11 = (r1 + ix1) * 8 + bq;
  };

  uint4 c00, c01, c10, c11;
  {
    int g00, g01, g10, g11;
    taps(0, g00, g01, g10, g11);
    c00 = xt4[g00]; c01 = xt4[g01]; c10 = xt4[g10]; c11 = xt4[g11];
  }

#pragma unroll
  for (int k = 0; k < KK; ++k) {
    // Prefetch next tap's corners before consuming this tap's.
    uint4 n00, n01, n10, n11;
    if (k < KK - 1) {
      int g00, g01, g10, g11;
      taps(k + 1, g00, g01, g10, g11);
      n00 = xt4[g00]; n01 = xt4[g01]; n10 = xt4[g10]; n11 = xt4[g11];
    }

    float bxf = floorf(s[k].x), byf = floorf(s[k].y);
    float fx = s[k].x - bxf, fy = s[k].y - byf;
    _Float16 w00 = (_Float16)((1.f - fx) * (1.f - fy));
    _Float16 w01 = (_Float16)(fx * (1.f - fy));
    _Float16 w10 = (_Float16)((1.f - fx) * fy);
    _Float16 w11 = (_Float16)(fx * fy);
    hf8 h00 = {w00, w00, w00, w00, w00, w00, w00, w00};
    hf8 h01 = {w01, w01, w01, w01, w01, w01, w01, w01};
    hf8 h10 = {w10, w10, w10, w10, w10, w10, w10, w10};
    hf8 h11 = {w11, w11, w11, w11, w11, w11, w11, w11};

    hf8 a = h00 * u4h(c00) + h01 * u4h(c01) + h10 * u4h(c10) + h11 * u4h(c11);

    const uint4* wk = wbl + (size_t)k * 256;   // per-k block = 64 o * 4 granules
    hf8 b0 = u4h(wk[0]);
    hf8 b1 = u4h(wk[64]);
    hf8 b2 = u4h(wk[128]);
    hf8 b3 = u4h(wk[192]);

    acc[0] = __builtin_amdgcn_mfma_f32_16x16x32_f16(a, b0, acc[0], 0, 0, 0);
    acc[1] = __builtin_amdgcn_mfma_f32_16x16x32_f16(a, b1, acc[1], 0, 0, 0);
    acc[2] = __builtin_amdgcn_mfma_f32_16x16x32_f16(a, b2, acc[2], 0, 0, 0);
    acc[3] = __builtin_amdgcn_mfma_f32_16x16x32_f16(a, b3, acc[3], 0, 0, 0);

    if (k < KK - 1) { c00 = n00; c01 = n01; c10 = n10; c11 = n11; }
  }

  // Epilogue: lane writes 4 consecutive pixels (rows quad*4..+3) for cout n.
  int hw0 = hw_base + quad * 4;
#pragma unroll
  for (int nt = 0; nt < 4; ++nt) {
    int n = nt * 16 + m;
    float bn = bias[n];
    float4 v = make_float4(acc[nt][0] + bn, acc[nt][1] + bn,
                           acc[nt][2] + bn, acc[nt][3] + bn);
    float* op = out + (size_t)(b * COUT + n) * HW_OUT + hw0;
    *(float4*)op = v;
  }
}

extern "C" void kernel_launch(void* const* d_in, const int* in_sizes, int n_in,
                              void* d_out, int out_size, void* d_ws, size_t ws_size,
                              hipStream_t stream) {
  const float* x  = (const float*)d_in[0];   // [B][CIN][H*W]
  const float* w  = (const float*)d_in[1];   // [COUT][CIN][KK]
  const float* bs = (const float*)d_in[2];   // [COUT]
  const float* sm = (const float*)d_in[3];   // [OH*OW][KK][2]
  float* out = (float*)d_out;                // [B][COUT][OH*OW]
  _Float16* xt = (_Float16*)d_ws;            // 16 MB scratch: (H*W, B, CIN) f16

  transpose_f16_lds<<<dim3(1024), dim3(256), 0, stream>>>(x, xt);
  mapped_conv_mfma<<<dim3(2048), dim3(512), 0, stream>>>(xt, w, bs, sm, out);
}

// Round 5
// 250.329 us; speedup vs baseline: 1.0340x; 1.0324x over previous
//
#include <hip/hip_runtime.h>
#include <hip/hip_fp16.h>

// Problem constants: B=2, CIN=32, COUT=64, K=9, H=256, W=512, OH=256, OW=512
#define HW_IN   131072
#define W_IN    512
#define H_IN    256
#define HW_OUT  131072
#define CIN     32
#define COUT    64
#define KK      9
#define BB      2

typedef _Float16 hf2 __attribute__((ext_vector_type(2)));
typedef _Float16 hf8 __attribute__((ext_vector_type(8)));
typedef float f32x4 __attribute__((ext_vector_type(4)));

static __device__ __forceinline__ hf8 u4h(uint4 u) {
  return __builtin_bit_cast(hf8, u);
}

// ---------------------------------------------------------------------------
// Kernel 1: direct transpose x (B,CIN,H*W) fp32 -> xt (H*W, B, CIN) f16.
// Thread = (hw, g), g = granule 0..7 of the pixel's 128B record; bc = g*8+c.
// Lanes within a wave: 8 g x 8 consecutive hw -> the uint4 store is a fully
// contiguous 1KB per wave; reads are 8 channel-plane streams of 32B segments
// whose other 32B halves are read by the neighboring wave (L1 hit).
// No LDS (R3's LDS version ran at 0.36 TB/s due to serialized ds_write_u16).
// ---------------------------------------------------------------------------
__global__ __launch_bounds__(256) void transpose_direct(
    const float* __restrict__ x, _Float16* __restrict__ xt) {
  int tid = blockIdx.x * 256 + threadIdx.x;   // [0, 1048576)
  int g   = tid & 7;                          // granule: bc = g*8 + c
  int hw  = tid >> 3;                         // [0, 131072)

  const float* src = x + (size_t)(g * 8) * HW_IN + hw;
  hf8 h;
#pragma unroll
  for (int c = 0; c < 8; ++c) h[c] = (_Float16)src[(size_t)c * HW_IN];
  *(hf8*)(xt + (size_t)hw * 64 + g * 8) = h;
}

// ---------------------------------------------------------------------------
// Kernel 2: fused gather + MFMA contraction — R2-best config (fastest of
// R2/R3/R4; the kernel is pinned at ~3 TB/s random L2-fill, so occupancy
// and software prefetch are neutral; VGPR 64 / 16 waves/CU was best).
// GEMM view: out[pix, o] = sum_{ck=k*32+c} samp[pix, ck] * W[o, ck].
// One wave = 16 pixels x 64 couts (4 N-tiles), K=288 = 9 taps x 32 channels.
// A-frag 16x16x32 f16: lane m=lane&15 -> pixel, quad=lane>>4 -> channel
// quarter; corner gather = one 64B line per 4-lane set. B-frags from LDS
// [k][o][c] f16 (36KB, conflict-free disjoint reads).
// ---------------------------------------------------------------------------
__global__ __launch_bounds__(256, 4) void mapped_conv_mfma(
    const _Float16* __restrict__ xt,
    const float* __restrict__ weight,   // [COUT][CIN][KK] fp32
    const float* __restrict__ bias,     // [COUT]
    const float* __restrict__ sm,       // [HW_OUT][KK][2] fp32
    float* __restrict__ out) {          // [BB][COUT][HW_OUT] fp32
  __shared__ __align__(16) _Float16 w_lds[KK * COUT * CIN];  // 36 KB

  int t = threadIdx.x;
  // Stage weights: w_lds[(k*64 + o)*32 + c] = W[o][c][k] as f16.
  for (int j = t; j < COUT * CIN * KK; j += 256) {
    unsigned ju = (unsigned)j;
    unsigned o  = ju / 288u;
    unsigned rr = ju % 288u;
    unsigned c  = rr / 9u;
    unsigned k  = rr % 9u;
    w_lds[(k * 64u + o) * 32u + c] = (_Float16)weight[ju];
  }
  __syncthreads();

  int wave = t >> 6;
  int lane = t & 63;
  int m    = lane & 15;   // A-row: pixel; B-col: cout within N-tile
  int quad = lane >> 4;   // channel quarter (A) / k-chunk (B) / row group (C)

  int pix_base = blockIdx.x * 64 + wave * 16;     // 4096 blocks x 4 waves
  int pix  = pix_base + m;
  int b    = pix_base >> 17;                      // wave-uniform
  int hw   = pix & (HW_OUT - 1);
  int hw_base = pix_base & (HW_OUT - 1);

  const uint4* xt4 = (const uint4*)xt;
  int bq = b * 4 + quad;   // uint4-granule within a pixel's 64 halves

  f32x4 acc[4] = {{0.f,0.f,0.f,0.f},{0.f,0.f,0.f,0.f},
                  {0.f,0.f,0.f,0.f},{0.f,0.f,0.f,0.f}};

  const float* smp = sm + (size_t)hw * (KK * 2);
  const uint4* wbl = (const uint4*)w_lds + (size_t)(m * 4 + quad);

#pragma unroll 3
  for (int k = 0; k < KK; ++k) {
    float sx = smp[k * 2 + 0];
    float sy = smp[k * 2 + 1];
    float bxf = floorf(sx), byf = floorf(sy);
    float fx = sx - bxf, fy = sy - byf;
    int ix0 = (int)bxf, iy0 = (int)byf;
    int ix1 = min(ix0 + 1, W_IN - 1);
    int iy1 = min(iy0 + 1, H_IN - 1);
    ix0 = max(min(ix0, W_IN - 1), 0); ix1 = max(ix1, 0);
    iy0 = max(min(iy0, H_IN - 1), 0); iy1 = max(iy1, 0);

    uint4 v00 = xt4[(iy0 * W_IN + ix0) * 8 + bq];
    uint4 v01 = xt4[(iy0 * W_IN + ix1) * 8 + bq];
    uint4 v10 = xt4[(iy1 * W_IN + ix0) * 8 + bq];
    uint4 v11 = xt4[(iy1 * W_IN + ix1) * 8 + bq];

    _Float16 w00 = (_Float16)((1.f - fx) * (1.f - fy));
    _Float16 w01 = (_Float16)(fx * (1.f - fy));
    _Float16 w10 = (_Float16)((1.f - fx) * fy);
    _Float16 w11 = (_Float16)(fx * fy);
    hf8 h00 = {w00, w00, w00, w00, w00, w00, w00, w00};
    hf8 h01 = {w01, w01, w01, w01, w01, w01, w01, w01};
    hf8 h10 = {w10, w10, w10, w10, w10, w10, w10, w10};
    hf8 h11 = {w11, w11, w11, w11, w11, w11, w11, w11};

    hf8 a = h00 * u4h(v00) + h01 * u4h(v01) + h10 * u4h(v10) + h11 * u4h(v11);

    const uint4* wk = wbl + (size_t)k * 256;   // per-k block = 64 o * 4 granules
    hf8 b0 = u4h(wk[0]);
    hf8 b1 = u4h(wk[64]);
    hf8 b2 = u4h(wk[128]);
    hf8 b3 = u4h(wk[192]);

    acc[0] = __builtin_amdgcn_mfma_f32_16x16x32_f16(a, b0, acc[0], 0, 0, 0);
    acc[1] = __builtin_amdgcn_mfma_f32_16x16x32_f16(a, b1, acc[1], 0, 0, 0);
    acc[2] = __builtin_amdgcn_mfma_f32_16x16x32_f16(a, b2, acc[2], 0, 0, 0);
    acc[3] = __builtin_amdgcn_mfma_f32_16x16x32_f16(a, b3, acc[3], 0, 0, 0);
  }

  // Epilogue: lane writes 4 consecutive pixels (rows quad*4..+3) for cout n.
  int hw0 = hw_base + quad * 4;
#pragma unroll
  for (int nt = 0; nt < 4; ++nt) {
    int n = nt * 16 + m;
    float bn = bias[n];
    float4 v = make_float4(acc[nt][0] + bn, acc[nt][1] + bn,
                           acc[nt][2] + bn, acc[nt][3] + bn);
    float* op = out + (size_t)(b * COUT + n) * HW_OUT + hw0;
    *(float4*)op = v;
  }
}

extern "C" void kernel_launch(void* const* d_in, const int* in_sizes, int n_in,
                              void* d_out, int out_size, void* d_ws, size_t ws_size,
                              hipStream_t stream) {
  const float* x  = (const float*)d_in[0];   // [B][CIN][H*W]
  const float* w  = (const float*)d_in[1];   // [COUT][CIN][KK]
  const float* bs = (const float*)d_in[2];   // [COUT]
  const float* sm = (const float*)d_in[3];   // [OH*OW][KK][2]
  float* out = (float*)d_out;                // [B][COUT][OH*OW]
  _Float16* xt = (_Float16*)d_ws;            // 16 MB scratch: (H*W, B, CIN) f16

  transpose_direct<<<dim3(4096), dim3(256), 0, stream>>>(x, xt);
  mapped_conv_mfma<<<dim3(4096), dim3(256), 0, stream>>>(xt, w, bs, sm, out);
}